// Round 4
// baseline (89584.399 us; speedup 1.0000x reference)
//
#include <hip/hip_runtime.h>
#include <hip/hip_bf16.h>

// tanh-approx GELU (JAX default) and its exact derivative
__device__ __forceinline__ float gelu_f(float x) {
  const float c = 0.7978845608028654f;
  float u = c * (x + 0.044715f * x * x * x);
  float t = tanhf(u);
  return 0.5f * x * (1.f + t);
}
__device__ __forceinline__ float gelu_grad_f(float x) {
  const float c = 0.7978845608028654f;
  float x2 = x * x;
  float u = c * (x + 0.044715f * x2 * x);
  float t = tanhf(u);
  return 0.5f * (1.f + t) + 0.5f * x * (1.f - t * t) * c * (1.f + 0.134145f * x2);
}

// ---------------------------------------------------------------------------
// Tiled fp32 GEMM: C[M,N] = act(A@B(+bias)).  64x64 tile, 16-deep K panel.
// A rows pass through a chunk mapping: grow(m) = (m/P)*bsRows + rowOff + m%P
// ACT: 0=none, 1=gelu (optionally store pre-act to Zbuf), 2=G-epilogue
//      (v = gscale*(pred - ci - delta)), 3=multiply by gelu'(Zbuf).
// ---------------------------------------------------------------------------
template<bool TRANSB, int ACT>
__global__ __launch_bounds__(256) void gemm_k(
    const float* __restrict__ A, const float* __restrict__ B, float* __restrict__ C,
    float* __restrict__ Zbuf, const float* __restrict__ bias,
    int M, int N, int K, int lda, int ldb,
    int P, int bsRows, int rowOff,
    const float* __restrict__ ci, int ciP, int ciBs, int ciOff,
    const float* __restrict__ delta, float gscale)
{
  __shared__ float As[16][68];
  __shared__ float Bs[16][68];
  const int bm = blockIdx.y * 64, bn = blockIdx.x * 64;
  const int tid = threadIdx.x;
  const int tr = tid >> 4, tc = tid & 15;
  float acc[4][4] = {};
  for (int k0 = 0; k0 < K; k0 += 16) {
    { // A tile (K is always a multiple of 16 here)
      const int e = tid * 4;
      const int m = e >> 4, kk = e & 15;
      const int gm = bm + m;
      const bool mv = gm < M;
      const long grow = (long)(gm / P) * bsRows + rowOff + (gm % P);
      const float* ap = A + grow * lda + k0 + kk;
      #pragma unroll
      for (int i = 0; i < 4; i++) {
        float v = 0.f;
        if (mv) v = ap[i];
        As[kk + i][m] = v;
      }
    }
    if (!TRANSB) {
      const int e = tid * 4;
      const int kk = e >> 6, n = e & 63;
      const int gn = bn + n;
      const float* bp = B + (long)(k0 + kk) * ldb + gn;
      #pragma unroll
      for (int i = 0; i < 4; i++) Bs[kk][n + i] = bp[i];
    } else {
      const int e = tid * 4;
      const int n = e >> 4, kk = e & 15;
      const int gn = bn + n;
      const float* bp = B + (long)gn * ldb + k0 + kk;
      #pragma unroll
      for (int i = 0; i < 4; i++) Bs[kk + i][n] = bp[i];
    }
    __syncthreads();
    #pragma unroll
    for (int kk = 0; kk < 16; kk++) {
      float a[4], b[4];
      #pragma unroll
      for (int i = 0; i < 4; i++) a[i] = As[kk][tr * 4 + i];
      #pragma unroll
      for (int j = 0; j < 4; j++) b[j] = Bs[kk][tc * 4 + j];
      #pragma unroll
      for (int i = 0; i < 4; i++)
        #pragma unroll
        for (int j = 0; j < 4; j++) acc[i][j] += a[i] * b[j];
    }
    __syncthreads();
  }
  #pragma unroll
  for (int i = 0; i < 4; i++) {
    const int m = bm + tr * 4 + i;
    if (m >= M) continue;
    #pragma unroll
    for (int j = 0; j < 4; j++) {
      const int n = bn + tc * 4 + j;
      if (n >= N) continue;
      float v = acc[i][j];
      if (bias) v += bias[n];
      if (ACT == 1) {
        if (Zbuf) Zbuf[(long)m * N + n] = v;
        v = gelu_f(v);
      } else if (ACT == 2) {
        const long crow = (long)(m / ciP) * ciBs + ciOff + (m % ciP);
        const float tgt = ci[crow * 1024 + n] + delta[(m / ciP) * 1024 + n];
        v = gscale * (v - tgt);
      } else if (ACT == 3) {
        v = v * gelu_grad_f(Zbuf[(long)m * N + n]);
      }
      C[(long)m * N + n] = v;
    }
  }
}

// ---------------------------------------------------------------------------
// Flash-style causal attention. One WG per (qtile=64, head, batch).
// Q,K,V fp32 [B*S, 1024], head h occupies cols h*64..h*64+63. KB=32.
// LDS: (64*65 + 2*32*65 + 64*33) * 4 = 41,728 B  (< 64 KiB)
// ---------------------------------------------------------------------------
__global__ __launch_bounds__(256) void attn_kernel(
    const float* __restrict__ Q, const float* __restrict__ K,
    const float* __restrict__ V, float* __restrict__ ctx)
{
  const int S = 2048, D = 1024;
  const int qt = blockIdx.x, h = blockIdx.y, b = blockIdx.z;
  const int q0 = qt * 64;
  __shared__ float Qs[64][65];
  __shared__ float Ks[32][65];
  __shared__ float Vs[32][65];
  __shared__ float Ss[64][33];
  const int tid = threadIdx.x;
  for (int e = tid; e < 4096; e += 256) {
    int r = e >> 6, d = e & 63;
    Qs[r][d] = Q[(long)(b * S + q0 + r) * D + h * 64 + d];
  }
  const int r = tid >> 2;
  const int g = tid & 3;
  const int dg8 = g * 8;
  const int dg16 = g * 16;
  float acc[16];
  #pragma unroll
  for (int i = 0; i < 16; i++) acc[i] = 0.f;
  float mrow = -1e30f, lrow = 0.f;
  for (int k0 = 0; k0 < q0 + 64; k0 += 32) {
    __syncthreads();
    for (int e = tid; e < 2048; e += 256) {
      int rr = e >> 6, d = e & 63;
      Ks[rr][d] = K[(long)(b * S + k0 + rr) * D + h * 64 + d];
      Vs[rr][d] = V[(long)(b * S + k0 + rr) * D + h * 64 + d];
    }
    __syncthreads();
    float sc[8];
    #pragma unroll
    for (int j = 0; j < 8; j++) sc[j] = 0.f;
    for (int d = 0; d < 64; d++) {
      float qd = Qs[r][d];
      #pragma unroll
      for (int j = 0; j < 8; j++) sc[j] += qd * Ks[dg8 + j][d];
    }
    float tmax = -1e30f;
    #pragma unroll
    for (int j = 0; j < 8; j++) {
      sc[j] *= 0.125f;  // 1/sqrt(64)
      if (k0 + dg8 + j > q0 + r) sc[j] = -1e30f;
      tmax = fmaxf(tmax, sc[j]);
    }
    tmax = fmaxf(tmax, __shfl_xor(tmax, 1));
    tmax = fmaxf(tmax, __shfl_xor(tmax, 2));
    const float newm = fmaxf(mrow, tmax);
    const float scale = __expf(mrow - newm);
    float psum = 0.f;
    #pragma unroll
    for (int j = 0; j < 8; j++) {
      sc[j] = __expf(sc[j] - newm);
      psum += sc[j];
    }
    psum += __shfl_xor(psum, 1);
    psum += __shfl_xor(psum, 2);
    lrow = lrow * scale + psum;
    mrow = newm;
    #pragma unroll
    for (int i = 0; i < 16; i++) acc[i] *= scale;
    #pragma unroll
    for (int j = 0; j < 8; j++) Ss[r][dg8 + j] = sc[j];
    __syncthreads();
    for (int c = 0; c < 32; c++) {
      float p = Ss[r][c];
      #pragma unroll
      for (int i = 0; i < 16; i++) acc[i] += p * Vs[c][dg16 + i];
    }
  }
  const float inv = 1.f / lrow;
  #pragma unroll
  for (int i = 0; i < 16; i++)
    ctx[(long)(b * S + q0 + r) * D + h * 64 + dg16 + i] = acc[i] * inv;
}

// ---------------------------------------------------------------------------
// Rank-R SGD update: W[d1,d2] -= lr * sum_r X[xrow(r), d1] * Y[r, d2]
// ---------------------------------------------------------------------------
__global__ __launch_bounds__(256) void rank_update(
    float* __restrict__ W, const float* __restrict__ X, const float* __restrict__ Y,
    int D1, int D2, int R, int xld,
    int P, int bsRows, int rowOff, float lr)
{
  __shared__ float Xs[128][33];
  __shared__ float Ys[128][33];
  const int d10 = blockIdx.y * 32, d20 = blockIdx.x * 32;
  const int tid = threadIdx.x;
  for (int e = tid; e < R * 32; e += 256) {
    int rr = e >> 5, i = e & 31;
    long xr = (long)(rr / P) * bsRows + rowOff + (rr % P);
    Xs[rr][i] = X[xr * xld + d10 + i];
    Ys[rr][i] = Y[(long)rr * D2 + d20 + i];
  }
  __syncthreads();
  const int jj = tid & 31;
  const int i0 = (tid >> 5) * 4;
  float acc[4] = {};
  for (int rr = 0; rr < R; rr++) {
    float y = Ys[rr][jj];
    #pragma unroll
    for (int i = 0; i < 4; i++) acc[i] += Xs[rr][i0 + i] * y;
  }
  #pragma unroll
  for (int i = 0; i < 4; i++) {
    long idx = (long)(d10 + i0 + i) * D2 + d20 + jj;
    W[idx] -= lr * acc[i];
  }
}

// b1 -= lr*colsum(dZ); b2 -= lr*colsum(G)
__global__ void bias_update(float* __restrict__ b1, const float* __restrict__ dZ,
                            float* __restrict__ b2, const float* __restrict__ Gm,
                            int R, int Hdim, int Ddim, float lr)
{
  int t = blockIdx.x * blockDim.x + threadIdx.x;
  if (t < Hdim) {
    float s = 0.f;
    for (int rr = 0; rr < R; rr++) s += dZ[(long)rr * Hdim + t];
    b1[t] -= lr * s;
  } else if (t < Hdim + Ddim) {
    int d = t - Hdim;
    float s = 0.f;
    for (int rr = 0; rr < R; rr++) s += Gm[(long)rr * Ddim + d];
    b2[d] -= lr * s;
  }
}

// Per-chunk teach means for both levels.
// dF[c*2048 + b*1024 + d], c<128 (chunk of 16); dS same with c<32 (chunk of 64)
__global__ void compute_deltas(const float* __restrict__ teach,
                               float* __restrict__ dF, float* __restrict__ dS)
{
  const int nF = 128 * 2048;
  const int nS = 32 * 2048;
  int t = blockIdx.x * blockDim.x + threadIdx.x;
  if (t < nF) {
    int c = t >> 11, b = (t >> 10) & 1, d = t & 1023;
    long base = ((long)(b * 2048 + c * 16)) * 1024 + d;
    float s = 0.f;
    for (int k = 0; k < 16; k++) s += teach[base + (long)k * 1024];
    dF[t] = s * (1.f / 16.f);
  } else if (t < nF + nS) {
    int u = t - nF;
    int c = u >> 11, b = (u >> 10) & 1, d = u & 1023;
    long base = ((long)(b * 2048 + c * 64)) * 1024 + d;
    float s = 0.f;
    for (int k = 0; k < 64; k++) s += teach[base + (long)k * 1024];
    dS[u] = s * (1.f / 64.f);
  }
}

extern "C" void kernel_launch(void* const* d_in, const int* in_sizes, int n_in,
                              void* d_out, int out_size, void* d_ws, size_t ws_size,
                              hipStream_t stream) {
  const float* x     = (const float*)d_in[0];
  const float* teach = (const float*)d_in[1];
  const float* wq    = (const float*)d_in[2];
  const float* wk    = (const float*)d_in[3];
  const float* wv    = (const float*)d_in[4];
  const float* wo    = (const float*)d_in[5];
  float* out = (float*)d_out;
  float* ws  = (float*)d_ws;

  // ---- d_out layout (floats): cms_out, then the 8 updated params ----
  const long P_W1F = 4194304;
  const long P_B1F = 8388608;
  const long P_W2F = 8392704;
  const long P_B2F = 12587008;
  const long P_W1S = 12588032;
  const long P_B1S = 16782336;
  const long P_W2S = 16786432;
  const long P_B2S = 20980736;   // end 20981760 == out_size

  // ---- ws layout (floats), total 25,503,744 = 102.0 MB ----
  // Phase A: Q/K/V/CTX in [0, 16.79M). Phase B overlays that region:
  const long O_Q   = 0;
  const long O_K   = 4194304;
  const long O_V   = 8388608;
  const long O_CTX = 12582912;
  const long O_H   = 0;          // MLP hidden row-block [512,4096]
  const long O_Z   = 2097152;    // [128,4096]
  const long O_A   = 2621440;    // [128,4096]
  const long O_DZ  = 3145728;    // [128,4096]
  const long O_G   = 3670016;    // [128,1024]
  const long O_INF = 16787456;   // in_fast [4096,1024]
  const long O_INS = 20981760;   // in_slow [4096,1024]
  const long O_DF  = 25176064;   // 262,144
  const long O_DS  = 25438208;   // 65,536

  const float LR = 1e-3f;

  // --- seed fp32 masters directly into d_out (updated in place by TTT) ---
  {
    const long poff[8] = {P_W1F, P_B1F, P_W2F, P_B2F, P_W1S, P_B1S, P_W2S, P_B2S};
    const size_t psz[8] = {4194304, 4096, 4194304, 1024, 4194304, 4096, 4194304, 1024};
    for (int i = 0; i < 8; i++)
      hipMemcpyAsync(out + poff[i], d_in[6 + i], psz[i] * sizeof(float),
                     hipMemcpyDeviceToDevice, stream);
  }

  // --- per-chunk teach means ---
  compute_deltas<<<dim3(1281), 256, 0, stream>>>(teach, ws + O_DF, ws + O_DS);

  // --- Q/K/V projections ---
  {
    dim3 grd(16, 64);
    gemm_k<false, 0><<<grd, 256, 0, stream>>>(
        x, wq, ws + O_Q, nullptr, nullptr, 4096, 1024, 1024, 1024, 1024,
        4096, 0, 0, nullptr, 1, 0, 0, nullptr, 0.f);
    gemm_k<false, 0><<<grd, 256, 0, stream>>>(
        x, wk, ws + O_K, nullptr, nullptr, 4096, 1024, 1024, 1024, 1024,
        4096, 0, 0, nullptr, 1, 0, 0, nullptr, 0.f);
    gemm_k<false, 0><<<grd, 256, 0, stream>>>(
        x, wv, ws + O_V, nullptr, nullptr, 4096, 1024, 1024, 1024, 1024,
        4096, 0, 0, nullptr, 1, 0, 0, nullptr, 0.f);
  }

  // --- causal attention ---
  attn_kernel<<<dim3(32, 16, 2), 256, 0, stream>>>(ws + O_Q, ws + O_K, ws + O_V, ws + O_CTX);

  // --- in_fast = ctx @ wo ---
  gemm_k<false, 0><<<dim3(16, 64), 256, 0, stream>>>(
      ws + O_CTX, wo, ws + O_INF, nullptr, nullptr, 4096, 1024, 1024, 1024, 1024,
      4096, 0, 0, nullptr, 1, 0, 0, nullptr, 0.f);

  // --- MLP forwards with BASE params (row-blocked, 512 rows via O_H).
  //     O_H overlays the dead Q region. ---
  for (int rb = 0; rb < 8; rb++) {
    gemm_k<false, 1><<<dim3(64, 8), 256, 0, stream>>>(
        ws + O_INF + (long)rb * 512 * 1024, out + P_W1F, ws + O_H, nullptr, out + P_B1F,
        512, 4096, 1024, 1024, 4096, 512, 0, 0, nullptr, 1, 0, 0, nullptr, 0.f);
    gemm_k<false, 0><<<dim3(16, 8), 256, 0, stream>>>(
        ws + O_H, out + P_W2F, ws + O_INS + (long)rb * 512 * 1024, nullptr, out + P_B2F,
        512, 1024, 4096, 4096, 1024, 512, 0, 0, nullptr, 1, 0, 0, nullptr, 0.f);
  }
  for (int rb = 0; rb < 8; rb++) {
    gemm_k<false, 1><<<dim3(64, 8), 256, 0, stream>>>(
        ws + O_INS + (long)rb * 512 * 1024, out + P_W1S, ws + O_H, nullptr, out + P_B1S,
        512, 4096, 1024, 1024, 4096, 512, 0, 0, nullptr, 1, 0, 0, nullptr, 0.f);
    gemm_k<false, 0><<<dim3(16, 8), 256, 0, stream>>>(
        ws + O_H, out + P_W2S, out + (long)rb * 512 * 1024, nullptr, out + P_B2S,
        512, 1024, 4096, 4096, 1024, 512, 0, 0, nullptr, 1, 0, 0, nullptr, 0.f);
  }

  // --- TTT updates: sequential chunk scans, updating masters in d_out ---
  for (int lvl = 0; lvl < 2; lvl++) {
    const int Pc = lvl ? 64 : 16;
    const int nc = lvl ? 32 : 128;
    const int R = 2 * Pc;
    const float gscale = 2.f / (float)R;
    const float* lin = lvl ? ws + O_INS : ws + O_INF;
    float* W1 = lvl ? out + P_W1S : out + P_W1F;
    float* B1 = lvl ? out + P_B1S : out + P_B1F;
    float* W2 = lvl ? out + P_W2S : out + P_W2F;
    float* B2 = lvl ? out + P_B2S : out + P_B2F;
    const float* dlt = lvl ? ws + O_DS : ws + O_DF;
    for (int c = 0; c < nc; c++) {
      const int off = c * Pc;
      const dim3 gH(64, (R + 63) / 64);   // N=4096 tiles
      const dim3 gD(16, (R + 63) / 64);   // N=1024 tiles
      // C1: z = ci@W1+b1 ; a = gelu(z)
      gemm_k<false, 1><<<gH, 256, 0, stream>>>(
          lin, W1, ws + O_A, ws + O_Z, B1, R, 4096, 1024, 1024, 4096,
          Pc, 2048, off, nullptr, 1, 0, 0, nullptr, 0.f);
      // C2: G = (2/R)*(a@W2+b2 - ci - delta)
      gemm_k<false, 2><<<gD, 256, 0, stream>>>(
          ws + O_A, W2, ws + O_G, nullptr, B2, R, 1024, 4096, 4096, 1024,
          R, 0, 0, lin, Pc, 2048, off, dlt + (long)c * 2048, gscale);
      // C3: dZ = (G@W2^T) * gelu'(z)
      gemm_k<true, 3><<<gH, 256, 0, stream>>>(
          ws + O_G, W2, ws + O_DZ, ws + O_Z, nullptr, R, 4096, 1024, 1024, 1024,
          R, 0, 0, nullptr, 1, 0, 0, nullptr, 0.f);
      // C4a: W1 -= lr * ci^T @ dZ
      rank_update<<<dim3(128, 32), 256, 0, stream>>>(
          W1, lin, ws + O_DZ, 1024, 4096, R, 1024, Pc, 2048, off, LR);
      // C4b: W2 -= lr * a^T @ G
      rank_update<<<dim3(32, 128), 256, 0, stream>>>(
          W2, ws + O_A, ws + O_G, 4096, 1024, R, 4096, R, 0, 0, LR);
      // C5: bias updates
      bias_update<<<dim3(20), 256, 0, stream>>>(B1, ws + O_DZ, B2, ws + O_G, R, 4096, 1024, LR);
    }
  }
}